// Round 1
// baseline (1121.429 us; speedup 1.0000x reference)
//
#include <hip/hip_runtime.h>

#define N_NODES 100000
#define N_EDGESC 1600000
#define IN_CH 128
#define HID 64
#define OUTC 40
#define NEG_SLOPE 0.2f

// ---- order-preserving float<->uint encoding for atomicMax ----
__device__ __forceinline__ unsigned fenc(float f) {
    unsigned u = __float_as_uint(f);
    return (u & 0x80000000u) ? ~u : (u | 0x80000000u);
}
__device__ __forceinline__ float fdec(unsigned k) {
    unsigned u = (k & 0x80000000u) ? (k ^ 0x80000000u) : ~k;
    return __uint_as_float(u);
}

// ---- GEMM1: h1 = x @ W1 ; al_src/al_dst = h1 @ a ----
// thread = one node; acc[64] in registers; W1 broadcast from LDS.
__global__ __launch_bounds__(256) void gemm1_kernel(
    const float* __restrict__ x, const float* __restrict__ W1,
    const float* __restrict__ a_src, const float* __restrict__ a_dst,
    float* __restrict__ h1, float* __restrict__ als, float* __restrict__ ald) {
    __shared__ float Ws[IN_CH * HID];      // 32 KB
    __shared__ float as_s[HID], ad_s[HID];
    for (int v = threadIdx.x; v < IN_CH * HID; v += blockDim.x) Ws[v] = W1[v];
    if (threadIdx.x < HID) { as_s[threadIdx.x] = a_src[threadIdx.x]; ad_s[threadIdx.x] = a_dst[threadIdx.x]; }
    __syncthreads();
    int n = blockIdx.x * blockDim.x + threadIdx.x;
    if (n >= N_NODES) return;

    float acc[HID];
#pragma unroll
    for (int c = 0; c < HID; c++) acc[c] = 0.f;

    const float4* xrow = reinterpret_cast<const float4*>(x + (size_t)n * IN_CH);
#pragma unroll 2
    for (int kq = 0; kq < IN_CH / 4; kq++) {
        float4 xv = xrow[kq];
#pragma unroll
        for (int j = 0; j < 4; j++) {
            float xs = (j == 0) ? xv.x : (j == 1) ? xv.y : (j == 2) ? xv.z : xv.w;
            const float4* wr = reinterpret_cast<const float4*>(&Ws[(kq * 4 + j) * HID]);
#pragma unroll
            for (int cq = 0; cq < HID / 4; cq++) {
                float4 wv = wr[cq];
                acc[cq * 4 + 0] += xs * wv.x;
                acc[cq * 4 + 1] += xs * wv.y;
                acc[cq * 4 + 2] += xs * wv.z;
                acc[cq * 4 + 3] += xs * wv.w;
            }
        }
    }
    float s1 = 0.f, s2 = 0.f;
    float4* hrow = reinterpret_cast<float4*>(h1 + (size_t)n * HID);
#pragma unroll
    for (int cq = 0; cq < HID / 4; cq++) {
        float4 o;
        o.x = acc[cq * 4 + 0]; o.y = acc[cq * 4 + 1]; o.z = acc[cq * 4 + 2]; o.w = acc[cq * 4 + 3];
        hrow[cq] = o;
#pragma unroll
        for (int j = 0; j < 4; j++) {
            s1 += acc[cq * 4 + j] * as_s[cq * 4 + j];
            s2 += acc[cq * 4 + j] * ad_s[cq * 4 + j];
        }
    }
    als[n] = s1;
    ald[n] = s2;
}

// ---- GEMM2: h2 = h2in @ W2 ; logits ----
__global__ __launch_bounds__(256) void gemm2_kernel(
    const float* __restrict__ hin, const float* __restrict__ W2,
    const float* __restrict__ a_src, const float* __restrict__ a_dst,
    float* __restrict__ h2, float* __restrict__ als, float* __restrict__ ald) {
    __shared__ float Ws[HID * OUTC];       // 10 KB
    __shared__ float as_s[OUTC], ad_s[OUTC];
    for (int v = threadIdx.x; v < HID * OUTC; v += blockDim.x) Ws[v] = W2[v];
    if (threadIdx.x < OUTC) { as_s[threadIdx.x] = a_src[threadIdx.x]; ad_s[threadIdx.x] = a_dst[threadIdx.x]; }
    __syncthreads();
    int n = blockIdx.x * blockDim.x + threadIdx.x;
    if (n >= N_NODES) return;

    float acc[OUTC];
#pragma unroll
    for (int c = 0; c < OUTC; c++) acc[c] = 0.f;

    const float4* xrow = reinterpret_cast<const float4*>(hin + (size_t)n * HID);
#pragma unroll 2
    for (int kq = 0; kq < HID / 4; kq++) {
        float4 xv = xrow[kq];
#pragma unroll
        for (int j = 0; j < 4; j++) {
            float xs = (j == 0) ? xv.x : (j == 1) ? xv.y : (j == 2) ? xv.z : xv.w;
            const float4* wr = reinterpret_cast<const float4*>(&Ws[(kq * 4 + j) * OUTC]);
#pragma unroll
            for (int cq = 0; cq < OUTC / 4; cq++) {
                float4 wv = wr[cq];
                acc[cq * 4 + 0] += xs * wv.x;
                acc[cq * 4 + 1] += xs * wv.y;
                acc[cq * 4 + 2] += xs * wv.z;
                acc[cq * 4 + 3] += xs * wv.w;
            }
        }
    }
    float s1 = 0.f, s2 = 0.f;
    float4* hrow = reinterpret_cast<float4*>(h2 + (size_t)n * OUTC);
#pragma unroll
    for (int cq = 0; cq < OUTC / 4; cq++) {
        float4 o;
        o.x = acc[cq * 4 + 0]; o.y = acc[cq * 4 + 1]; o.z = acc[cq * 4 + 2]; o.w = acc[cq * 4 + 3];
        hrow[cq] = o;
#pragma unroll
        for (int j = 0; j < 4; j++) {
            s1 += acc[cq * 4 + j] * as_s[cq * 4 + j];
            s2 += acc[cq * 4 + j] * ad_s[cq * 4 + j];
        }
    }
    als[n] = s1;
    ald[n] = s2;
}

// ---- edge pass A: segment max of leakyrelu(al_src[s]+al_dst[d]) over dst ----
__global__ __launch_bounds__(256) void edge_max_kernel(
    const int* __restrict__ src, const int* __restrict__ dst,
    const float* __restrict__ als, const float* __restrict__ ald,
    unsigned* __restrict__ mo) {
    int i = blockIdx.x * blockDim.x + threadIdx.x;
    if (i >= N_EDGESC + N_NODES) return;
    int s, d;
    if (i < N_EDGESC) { s = src[i]; d = dst[i]; } else { s = d = i - N_EDGESC; }
    float e = als[s] + ald[d];
    e = e > 0.f ? e : NEG_SLOPE * e;
    atomicMax(&mo[d], fenc(e));
}

// ---- edge pass B: wave per edge; lane=channel; scatter w*h[src] into acc[dst] ----
template <int C>
__global__ __launch_bounds__(256) void edge_scatter_kernel(
    const int* __restrict__ src, const int* __restrict__ dst,
    const float* __restrict__ als, const float* __restrict__ ald,
    const unsigned* __restrict__ mo, const float* __restrict__ h,
    float* __restrict__ acc, float* __restrict__ z) {
    int widx = (blockIdx.x * blockDim.x + threadIdx.x) >> 6;
    int lane = threadIdx.x & 63;
    if (widx >= N_EDGESC + N_NODES) return;
    int s, d;
    if (widx < N_EDGESC) { s = src[widx]; d = dst[widx]; } else { s = d = widx - N_EDGESC; }
    float e = als[s] + ald[d];
    e = e > 0.f ? e : NEG_SLOPE * e;
    float m = fdec(mo[d]);
    float w = __expf(e - m);
    if (lane == 0) atomicAdd(&z[d], w);
    if (lane < C) atomicAdd(&acc[(size_t)d * C + lane], w * h[(size_t)s * C + lane]);
}

// ---- epilogue 1: relu(acc/(z+eps) + b) in place ----
__global__ __launch_bounds__(256) void epilogue1_kernel(
    float* __restrict__ B, const float* __restrict__ z, const float* __restrict__ b1) {
    int i = blockIdx.x * blockDim.x + threadIdx.x;
    if (i >= N_NODES * HID) return;
    int n = i >> 6, c = i & 63;
    float v = B[i] / (z[n] + 1e-16f) + b1[c];
    B[i] = v > 0.f ? v : 0.f;
}

// ---- epilogue 2: acc/(z+eps)+b then log_softmax; wave per node ----
__global__ __launch_bounds__(256) void epilogue2_kernel(
    const float* __restrict__ acc2, const float* __restrict__ z2,
    const float* __restrict__ b2, float* __restrict__ out) {
    int n = (blockIdx.x * blockDim.x + threadIdx.x) >> 6;
    int lane = threadIdx.x & 63;
    if (n >= N_NODES) return;
    float myv = 0.f;
    float v = -1e30f;
    if (lane < OUTC) {
        myv = acc2[(size_t)n * OUTC + lane] / (z2[n] + 1e-16f) + b2[lane];
        v = myv;
    }
#pragma unroll
    for (int o = 32; o > 0; o >>= 1) v = fmaxf(v, __shfl_xor(v, o));
    float ex = (lane < OUTC) ? __expf(myv - v) : 0.f;
#pragma unroll
    for (int o = 32; o > 0; o >>= 1) ex += __shfl_xor(ex, o);
    // ex now holds sum over lanes
    if (lane < OUTC) out[(size_t)n * OUTC + lane] = myv - v - logf(ex);
}

extern "C" void kernel_launch(void* const* d_in, const int* in_sizes, int n_in,
                              void* d_out, int out_size, void* d_ws, size_t ws_size,
                              hipStream_t stream) {
    const float* x   = (const float*)d_in[0];
    const int*   ei  = (const int*)d_in[1];
    const float* W1  = (const float*)d_in[2];
    const float* as1 = (const float*)d_in[3];
    const float* ad1 = (const float*)d_in[4];
    const float* b1  = (const float*)d_in[5];
    const float* W2  = (const float*)d_in[6];
    const float* as2 = (const float*)d_in[7];
    const float* ad2 = (const float*)d_in[8];
    const float* b2  = (const float*)d_in[9];
    float* out = (float*)d_out;

    float* A    = (float*)d_ws;                       // N*64 : h1, later h2 (first N*40)
    float* B    = A + (size_t)N_NODES * 64;           // N*64 : acc1 -> h2in -> acc2
    float* als1 = B + (size_t)N_NODES * 64;
    float* ald1 = als1 + N_NODES;
    unsigned* m1 = (unsigned*)(ald1 + N_NODES);
    float* z1   = (float*)(m1 + N_NODES);
    float* als2 = z1 + N_NODES;
    float* ald2 = als2 + N_NODES;
    unsigned* m2 = (unsigned*)(ald2 + N_NODES);
    float* z2   = (float*)(m2 + N_NODES);

    const int* srcA = ei;
    const int* dstA = ei + N_EDGESC;
    const int Etot = N_EDGESC + N_NODES;

    // zero acc1 + all scalar arrays (fenc init 0 == below any real value)
    hipMemsetAsync(B, 0, ((size_t)N_NODES * 64 + 8 * (size_t)N_NODES) * sizeof(float), stream);

    gemm1_kernel<<<(N_NODES + 255) / 256, 256, 0, stream>>>(x, W1, as1, ad1, A, als1, ald1);
    edge_max_kernel<<<(Etot + 255) / 256, 256, 0, stream>>>(srcA, dstA, als1, ald1, m1);
    edge_scatter_kernel<64><<<(Etot + 3) / 4, 256, 0, stream>>>(srcA, dstA, als1, ald1, m1, A, B, z1);
    epilogue1_kernel<<<(N_NODES * HID + 255) / 256, 256, 0, stream>>>(B, z1, b1);
    gemm2_kernel<<<(N_NODES + 255) / 256, 256, 0, stream>>>(B, W2, as2, ad2, A, als2, ald2);
    hipMemsetAsync(B, 0, (size_t)N_NODES * OUTC * sizeof(float), stream);
    edge_max_kernel<<<(Etot + 255) / 256, 256, 0, stream>>>(srcA, dstA, als2, ald2, m2);
    edge_scatter_kernel<40><<<(Etot + 3) / 4, 256, 0, stream>>>(srcA, dstA, als2, ald2, m2, A, B, z2);
    epilogue2_kernel<<<(N_NODES + 3) / 4, 256, 0, stream>>>(B, z2, b2, out);
}

// Round 2
// 651.321 us; speedup vs baseline: 1.7218x; 1.7218x over previous
//
#include <hip/hip_runtime.h>

#define N_NODES 100000
#define N_EDGESC 1600000
#define ETOT (N_EDGESC + N_NODES)
#define IN_CH 128
#define HID 64
#define OUTC 40
#define NEG_SLOPE 0.2f
#define SCAN_CHUNK 1024
#define NSCAN_BLOCKS ((N_NODES + SCAN_CHUNK - 1) / SCAN_CHUNK)  // 98

// ================= counting sort of edges by dst =================

__global__ __launch_bounds__(256) void hist_kernel(const int* __restrict__ dst,
                                                   int* __restrict__ cnt) {
    int i = blockIdx.x * blockDim.x + threadIdx.x;
    if (i >= ETOT) return;
    int d = (i < N_EDGESC) ? dst[i] : (i - N_EDGESC);
    atomicAdd(&cnt[d], 1);
}

__global__ __launch_bounds__(256) void scanA_kernel(const int* __restrict__ cnt,
                                                    int* __restrict__ off,
                                                    int* __restrict__ blockSum) {
    __shared__ int sdata[256];
    int base = blockIdx.x * SCAN_CHUNK;
    int t = threadIdx.x;
    int c[4];
    int s = 0;
#pragma unroll
    for (int j = 0; j < 4; j++) {
        int idx = base + t * 4 + j;
        c[j] = (idx < N_NODES) ? cnt[idx] : 0;
        s += c[j];
    }
    sdata[t] = s;
    __syncthreads();
    for (int o = 1; o < 256; o <<= 1) {
        int v = (t >= o) ? sdata[t - o] : 0;
        __syncthreads();
        sdata[t] += v;
        __syncthreads();
    }
    int run = sdata[t] - s;  // exclusive base for this thread
#pragma unroll
    for (int j = 0; j < 4; j++) {
        int idx = base + t * 4 + j;
        if (idx < N_NODES) off[idx] = run;
        run += c[j];
    }
    if (t == 255) blockSum[blockIdx.x] = sdata[255];
}

__global__ void scanB_kernel(int* __restrict__ blockSum) {
    __shared__ int s[128];
    int t = threadIdx.x;
    if (t < NSCAN_BLOCKS) s[t] = blockSum[t];
    __syncthreads();
    if (t == 0) {
        int run = 0;
        for (int i = 0; i < NSCAN_BLOCKS; i++) { int v = s[i]; s[i] = run; run += v; }
    }
    __syncthreads();
    if (t < NSCAN_BLOCKS) blockSum[t] = s[t];
}

__global__ __launch_bounds__(256) void scanC_kernel(int* __restrict__ off,
                                                    const int* __restrict__ blockSum,
                                                    int* __restrict__ cursor) {
    int i = blockIdx.x * blockDim.x + threadIdx.x;
    if (i == 0) off[N_NODES] = ETOT;
    if (i >= N_NODES) return;
    int v = off[i] + blockSum[i >> 10];  // i / SCAN_CHUNK
    off[i] = v;
    cursor[i] = v;
}

__global__ __launch_bounds__(256) void scatter_kernel(const int* __restrict__ src,
                                                      const int* __restrict__ dst,
                                                      int* __restrict__ cursor,
                                                      int* __restrict__ ssrc) {
    int i = blockIdx.x * blockDim.x + threadIdx.x;
    if (i >= ETOT) return;
    int s, d;
    if (i < N_EDGESC) { s = src[i]; d = dst[i]; } else { s = d = i - N_EDGESC; }
    int pos = atomicAdd(&cursor[d], 1);
    ssrc[pos] = s;
}

// ================= GEMMs (thread-per-node, W in LDS broadcast) =================

__global__ __launch_bounds__(256) void gemm1_kernel(
    const float* __restrict__ x, const float* __restrict__ W1,
    const float* __restrict__ a_src, const float* __restrict__ a_dst,
    float* __restrict__ h1, float* __restrict__ als, float* __restrict__ ald) {
    __shared__ float Ws[IN_CH * HID];
    __shared__ float as_s[HID], ad_s[HID];
    for (int v = threadIdx.x; v < IN_CH * HID; v += blockDim.x) Ws[v] = W1[v];
    if (threadIdx.x < HID) { as_s[threadIdx.x] = a_src[threadIdx.x]; ad_s[threadIdx.x] = a_dst[threadIdx.x]; }
    __syncthreads();
    int n = blockIdx.x * blockDim.x + threadIdx.x;
    if (n >= N_NODES) return;

    float acc[HID];
#pragma unroll
    for (int c = 0; c < HID; c++) acc[c] = 0.f;

    const float4* xrow = reinterpret_cast<const float4*>(x + (size_t)n * IN_CH);
#pragma unroll 2
    for (int kq = 0; kq < IN_CH / 4; kq++) {
        float4 xv = xrow[kq];
#pragma unroll
        for (int j = 0; j < 4; j++) {
            float xs = (j == 0) ? xv.x : (j == 1) ? xv.y : (j == 2) ? xv.z : xv.w;
            const float4* wr = reinterpret_cast<const float4*>(&Ws[(kq * 4 + j) * HID]);
#pragma unroll
            for (int cq = 0; cq < HID / 4; cq++) {
                float4 wv = wr[cq];
                acc[cq * 4 + 0] += xs * wv.x;
                acc[cq * 4 + 1] += xs * wv.y;
                acc[cq * 4 + 2] += xs * wv.z;
                acc[cq * 4 + 3] += xs * wv.w;
            }
        }
    }
    float s1 = 0.f, s2 = 0.f;
    float4* hrow = reinterpret_cast<float4*>(h1 + (size_t)n * HID);
#pragma unroll
    for (int cq = 0; cq < HID / 4; cq++) {
        float4 o;
        o.x = acc[cq * 4 + 0]; o.y = acc[cq * 4 + 1]; o.z = acc[cq * 4 + 2]; o.w = acc[cq * 4 + 3];
        hrow[cq] = o;
#pragma unroll
        for (int j = 0; j < 4; j++) {
            s1 += acc[cq * 4 + j] * as_s[cq * 4 + j];
            s2 += acc[cq * 4 + j] * ad_s[cq * 4 + j];
        }
    }
    als[n] = s1;
    ald[n] = s2;
}

__global__ __launch_bounds__(256) void gemm2_kernel(
    const float* __restrict__ hin, const float* __restrict__ W2,
    const float* __restrict__ a_src, const float* __restrict__ a_dst,
    float* __restrict__ h2, float* __restrict__ als, float* __restrict__ ald) {
    __shared__ float Ws[HID * OUTC];
    __shared__ float as_s[OUTC], ad_s[OUTC];
    for (int v = threadIdx.x; v < HID * OUTC; v += blockDim.x) Ws[v] = W2[v];
    if (threadIdx.x < OUTC) { as_s[threadIdx.x] = a_src[threadIdx.x]; ad_s[threadIdx.x] = a_dst[threadIdx.x]; }
    __syncthreads();
    int n = blockIdx.x * blockDim.x + threadIdx.x;
    if (n >= N_NODES) return;

    float acc[OUTC];
#pragma unroll
    for (int c = 0; c < OUTC; c++) acc[c] = 0.f;

    const float4* xrow = reinterpret_cast<const float4*>(hin + (size_t)n * HID);
#pragma unroll 2
    for (int kq = 0; kq < HID / 4; kq++) {
        float4 xv = xrow[kq];
#pragma unroll
        for (int j = 0; j < 4; j++) {
            float xs = (j == 0) ? xv.x : (j == 1) ? xv.y : (j == 2) ? xv.z : xv.w;
            const float4* wr = reinterpret_cast<const float4*>(&Ws[(kq * 4 + j) * OUTC]);
#pragma unroll
            for (int cq = 0; cq < OUTC / 4; cq++) {
                float4 wv = wr[cq];
                acc[cq * 4 + 0] += xs * wv.x;
                acc[cq * 4 + 1] += xs * wv.y;
                acc[cq * 4 + 2] += xs * wv.z;
                acc[cq * 4 + 3] += xs * wv.w;
            }
        }
    }
    float s1 = 0.f, s2 = 0.f;
    float4* hrow = reinterpret_cast<float4*>(h2 + (size_t)n * OUTC);
#pragma unroll
    for (int cq = 0; cq < OUTC / 4; cq++) {
        float4 o;
        o.x = acc[cq * 4 + 0]; o.y = acc[cq * 4 + 1]; o.z = acc[cq * 4 + 2]; o.w = acc[cq * 4 + 3];
        hrow[cq] = o;
#pragma unroll
        for (int j = 0; j < 4; j++) {
            s1 += acc[cq * 4 + j] * as_s[cq * 4 + j];
            s2 += acc[cq * 4 + j] * ad_s[cq * 4 + j];
        }
    }
    als[n] = s1;
    ald[n] = s2;
}

// ================= aggregation: wave per dst node, gather formulation =================
// FINAL=false: out = relu(acc/z + bias)   (layer 1)
// FINAL=true : out = log_softmax(acc/z + bias)   (layer 2)
template <int C, bool FINAL>
__global__ __launch_bounds__(256) void agg_kernel(
    const int* __restrict__ off, const int* __restrict__ ssrc,
    const float* __restrict__ als, const float* __restrict__ ald,
    const float* __restrict__ h, const float* __restrict__ bias,
    float* __restrict__ outp) {
    int d = (blockIdx.x * blockDim.x + threadIdx.x) >> 6;
    int lane = threadIdx.x & 63;
    if (d >= N_NODES) return;
    int o0 = off[d], o1 = off[d + 1];
    float aldd = ald[d];

    // phase A: segment max (lane-parallel over edges)
    float mloc = -1e30f;
    for (int j = o0 + lane; j < o1; j += 64) {
        float e = als[ssrc[j]] + aldd;
        e = e > 0.f ? e : NEG_SLOPE * e;
        mloc = fmaxf(mloc, e);
    }
#pragma unroll
    for (int o = 32; o; o >>= 1) mloc = fmaxf(mloc, __shfl_xor(mloc, o));

    // phase B: denominator
    float sloc = 0.f;
    for (int j = o0 + lane; j < o1; j += 64) {
        float e = als[ssrc[j]] + aldd;
        e = e > 0.f ? e : NEG_SLOPE * e;
        sloc += __expf(e - mloc);
    }
#pragma unroll
    for (int o = 32; o; o >>= 1) sloc += __shfl_xor(sloc, o);
    float inv = 1.0f / (sloc + 1e-16f);

    // phase C: weighted feature gather (lane = channel, serial over edges)
    float acc = 0.f;
    for (int j = o0; j < o1; ++j) {
        int s = ssrc[j];  // wave-uniform
        float e = als[s] + aldd;
        e = e > 0.f ? e : NEG_SLOPE * e;
        float w = __expf(e - mloc);
        if (lane < C) acc += w * h[(size_t)s * C + lane];
    }

    if (!FINAL) {
        if (lane < C) {
            float v = acc * inv + bias[lane];
            outp[(size_t)d * C + lane] = v > 0.f ? v : 0.f;
        }
    } else {
        float v = (lane < C) ? acc * inv + bias[lane] : -1e30f;
        float mv = v;
#pragma unroll
        for (int o = 32; o; o >>= 1) mv = fmaxf(mv, __shfl_xor(mv, o));
        float ex = (lane < C) ? __expf(v - mv) : 0.f;
        float se = ex;
#pragma unroll
        for (int o = 32; o; o >>= 1) se += __shfl_xor(se, o);
        if (lane < C) outp[(size_t)d * C + lane] = v - mv - logf(se);
    }
}

extern "C" void kernel_launch(void* const* d_in, const int* in_sizes, int n_in,
                              void* d_out, int out_size, void* d_ws, size_t ws_size,
                              hipStream_t stream) {
    const float* x   = (const float*)d_in[0];
    const int*   ei  = (const int*)d_in[1];
    const float* W1  = (const float*)d_in[2];
    const float* as1 = (const float*)d_in[3];
    const float* ad1 = (const float*)d_in[4];
    const float* b1  = (const float*)d_in[5];
    const float* W2  = (const float*)d_in[6];
    const float* as2 = (const float*)d_in[7];
    const float* ad2 = (const float*)d_in[8];
    const float* b2  = (const float*)d_in[9];
    float* out = (float*)d_out;

    float* A    = (float*)d_ws;                        // N*64 : h1, then h2 (N*40)
    float* B    = A + (size_t)N_NODES * 64;            // N*64 : layer-1 output / gemm2 input
    float* als  = B + (size_t)N_NODES * 64;            // N (reused both layers)
    float* ald  = als + N_NODES;                       // N
    int* cnt    = (int*)(ald + N_NODES);               // N (reused as cursor)
    int* off    = cnt + N_NODES;                       // N+1
    int* blockSum = off + (N_NODES + 1);               // 256 pad
    int* ssrc   = blockSum + 256;                      // ETOT

    const int* srcA = ei;
    const int* dstA = ei + N_EDGESC;

    // ---- build dst-sorted edge structure (shared by both layers) ----
    hipMemsetAsync(cnt, 0, N_NODES * sizeof(int), stream);
    hist_kernel<<<(ETOT + 255) / 256, 256, 0, stream>>>(dstA, cnt);
    scanA_kernel<<<NSCAN_BLOCKS, 256, 0, stream>>>(cnt, off, blockSum);
    scanB_kernel<<<1, 128, 0, stream>>>(blockSum);
    scanC_kernel<<<(N_NODES + 255) / 256, 256, 0, stream>>>(off, blockSum, cnt);
    scatter_kernel<<<(ETOT + 255) / 256, 256, 0, stream>>>(srcA, dstA, cnt, ssrc);

    // ---- layer 1 ----
    gemm1_kernel<<<(N_NODES + 255) / 256, 256, 0, stream>>>(x, W1, as1, ad1, A, als, ald);
    agg_kernel<HID, false><<<(N_NODES * 64 + 255) / 256, 256, 0, stream>>>(off, ssrc, als, ald, A, b1, B);

    // ---- layer 2 ----
    gemm2_kernel<<<(N_NODES + 255) / 256, 256, 0, stream>>>(B, W2, as2, ad2, A, als, ald);
    agg_kernel<OUTC, true><<<(N_NODES * 64 + 255) / 256, 256, 0, stream>>>(off, ssrc, als, ald, A, b2, out);
}

// Round 3
// 427.648 us; speedup vs baseline: 2.6223x; 1.5230x over previous
//
#include <hip/hip_runtime.h>

#define N_NODES 100000
#define N_EDGESC 1600000
#define ETOT (N_EDGESC + N_NODES)
#define IN_CH 128
#define HID 64
#define OUTC 40
#define NEG_SLOPE 0.2f
#define SCAN_CHUNK 1024
#define NSCAN_BLOCKS ((N_NODES + SCAN_CHUNK - 1) / SCAN_CHUNK)  // 98
#define SEG_CAP 128   // LDS-staged edges per segment (max in-degree ~45 for Poisson(16); fallback recomputes)

// ================= counting sort of edges by dst =================

__global__ __launch_bounds__(256) void hist_kernel(const int* __restrict__ dst,
                                                   int* __restrict__ cnt) {
    int i = blockIdx.x * blockDim.x + threadIdx.x;
    if (i >= ETOT) return;
    int d = (i < N_EDGESC) ? dst[i] : (i - N_EDGESC);
    atomicAdd(&cnt[d], 1);
}

__global__ __launch_bounds__(256) void scanA_kernel(const int* __restrict__ cnt,
                                                    int* __restrict__ off,
                                                    int* __restrict__ blockSum) {
    __shared__ int sdata[256];
    int base = blockIdx.x * SCAN_CHUNK;
    int t = threadIdx.x;
    int c[4];
    int s = 0;
#pragma unroll
    for (int j = 0; j < 4; j++) {
        int idx = base + t * 4 + j;
        c[j] = (idx < N_NODES) ? cnt[idx] : 0;
        s += c[j];
    }
    sdata[t] = s;
    __syncthreads();
    for (int o = 1; o < 256; o <<= 1) {
        int v = (t >= o) ? sdata[t - o] : 0;
        __syncthreads();
        sdata[t] += v;
        __syncthreads();
    }
    int run = sdata[t] - s;
#pragma unroll
    for (int j = 0; j < 4; j++) {
        int idx = base + t * 4 + j;
        if (idx < N_NODES) off[idx] = run;
        run += c[j];
    }
    if (t == 255) blockSum[blockIdx.x] = sdata[255];
}

__global__ void scanB_kernel(int* __restrict__ blockSum) {
    __shared__ int s[128];
    int t = threadIdx.x;
    if (t < NSCAN_BLOCKS) s[t] = blockSum[t];
    __syncthreads();
    if (t == 0) {
        int run = 0;
        for (int i = 0; i < NSCAN_BLOCKS; i++) { int v = s[i]; s[i] = run; run += v; }
    }
    __syncthreads();
    if (t < NSCAN_BLOCKS) blockSum[t] = s[t];
}

__global__ __launch_bounds__(256) void scanC_kernel(int* __restrict__ off,
                                                    const int* __restrict__ blockSum,
                                                    int* __restrict__ cursor) {
    int i = blockIdx.x * blockDim.x + threadIdx.x;
    if (i == 0) off[N_NODES] = ETOT;
    if (i >= N_NODES) return;
    int v = off[i] + blockSum[i >> 10];
    off[i] = v;
    cursor[i] = v;
}

__global__ __launch_bounds__(256) void scatter_kernel(const int* __restrict__ src,
                                                      const int* __restrict__ dst,
                                                      int* __restrict__ cursor,
                                                      int* __restrict__ ssrc) {
    int i = blockIdx.x * blockDim.x + threadIdx.x;
    if (i >= ETOT) return;
    int s, d;
    if (i < N_EDGESC) { s = src[i]; d = dst[i]; } else { s = d = i - N_EDGESC; }
    int pos = atomicAdd(&cursor[d], 1);
    ssrc[pos] = s;
}

// ================= GEMMs (thread-per-node, W in LDS broadcast) =================

__global__ __launch_bounds__(256) void gemm1_kernel(
    const float* __restrict__ x, const float* __restrict__ W1,
    const float* __restrict__ a_src, const float* __restrict__ a_dst,
    float* __restrict__ h1, float* __restrict__ als, float* __restrict__ ald) {
    __shared__ float Ws[IN_CH * HID];
    __shared__ float as_s[HID], ad_s[HID];
    for (int v = threadIdx.x; v < IN_CH * HID; v += blockDim.x) Ws[v] = W1[v];
    if (threadIdx.x < HID) { as_s[threadIdx.x] = a_src[threadIdx.x]; ad_s[threadIdx.x] = a_dst[threadIdx.x]; }
    __syncthreads();
    int n = blockIdx.x * blockDim.x + threadIdx.x;
    if (n >= N_NODES) return;

    float acc[HID];
#pragma unroll
    for (int c = 0; c < HID; c++) acc[c] = 0.f;

    const float4* xrow = reinterpret_cast<const float4*>(x + (size_t)n * IN_CH);
#pragma unroll 2
    for (int kq = 0; kq < IN_CH / 4; kq++) {
        float4 xv = xrow[kq];
#pragma unroll
        for (int j = 0; j < 4; j++) {
            float xs = (j == 0) ? xv.x : (j == 1) ? xv.y : (j == 2) ? xv.z : xv.w;
            const float4* wr = reinterpret_cast<const float4*>(&Ws[(kq * 4 + j) * HID]);
#pragma unroll
            for (int cq = 0; cq < HID / 4; cq++) {
                float4 wv = wr[cq];
                acc[cq * 4 + 0] += xs * wv.x;
                acc[cq * 4 + 1] += xs * wv.y;
                acc[cq * 4 + 2] += xs * wv.z;
                acc[cq * 4 + 3] += xs * wv.w;
            }
        }
    }
    float s1 = 0.f, s2 = 0.f;
    float4* hrow = reinterpret_cast<float4*>(h1 + (size_t)n * HID);
#pragma unroll
    for (int cq = 0; cq < HID / 4; cq++) {
        float4 o;
        o.x = acc[cq * 4 + 0]; o.y = acc[cq * 4 + 1]; o.z = acc[cq * 4 + 2]; o.w = acc[cq * 4 + 3];
        hrow[cq] = o;
#pragma unroll
        for (int j = 0; j < 4; j++) {
            s1 += acc[cq * 4 + j] * as_s[cq * 4 + j];
            s2 += acc[cq * 4 + j] * ad_s[cq * 4 + j];
        }
    }
    als[n] = s1;
    ald[n] = s2;
}

__global__ __launch_bounds__(256) void gemm2_kernel(
    const float* __restrict__ hin, const float* __restrict__ W2,
    const float* __restrict__ a_src, const float* __restrict__ a_dst,
    float* __restrict__ h2, float* __restrict__ als, float* __restrict__ ald) {
    __shared__ float Ws[HID * OUTC];
    __shared__ float as_s[OUTC], ad_s[OUTC];
    for (int v = threadIdx.x; v < HID * OUTC; v += blockDim.x) Ws[v] = W2[v];
    if (threadIdx.x < OUTC) { as_s[threadIdx.x] = a_src[threadIdx.x]; ad_s[threadIdx.x] = a_dst[threadIdx.x]; }
    __syncthreads();
    int n = blockIdx.x * blockDim.x + threadIdx.x;
    if (n >= N_NODES) return;

    float acc[OUTC];
#pragma unroll
    for (int c = 0; c < OUTC; c++) acc[c] = 0.f;

    const float4* xrow = reinterpret_cast<const float4*>(hin + (size_t)n * HID);
#pragma unroll 2
    for (int kq = 0; kq < HID / 4; kq++) {
        float4 xv = xrow[kq];
#pragma unroll
        for (int j = 0; j < 4; j++) {
            float xs = (j == 0) ? xv.x : (j == 1) ? xv.y : (j == 2) ? xv.z : xv.w;
            const float4* wr = reinterpret_cast<const float4*>(&Ws[(kq * 4 + j) * OUTC]);
#pragma unroll
            for (int cq = 0; cq < OUTC / 4; cq++) {
                float4 wv = wr[cq];
                acc[cq * 4 + 0] += xs * wv.x;
                acc[cq * 4 + 1] += xs * wv.y;
                acc[cq * 4 + 2] += xs * wv.z;
                acc[cq * 4 + 3] += xs * wv.w;
            }
        }
    }
    float s1 = 0.f, s2 = 0.f;
    float4* hrow = reinterpret_cast<float4*>(h2 + (size_t)n * OUTC);
#pragma unroll
    for (int cq = 0; cq < OUTC / 4; cq++) {
        float4 o;
        o.x = acc[cq * 4 + 0]; o.y = acc[cq * 4 + 1]; o.z = acc[cq * 4 + 2]; o.w = acc[cq * 4 + 3];
        hrow[cq] = o;
#pragma unroll
        for (int j = 0; j < 4; j++) {
            s1 += acc[cq * 4 + j] * as_s[cq * 4 + j];
            s2 += acc[cq * 4 + j] * ad_s[cq * 4 + j];
        }
    }
    als[n] = s1;
    ald[n] = s2;
}

// ================= aggregation: wave per dst node, LDS-staged gather =================
// Phase A: coalesced ssrc read + random als gather; stage s,e in LDS; wave-max.
// Phase B: w=exp(e-m) from LDS; stage w; wave-sum.
// Phase C: half-wave per edge (2 edges in flight, x2 unroll), float2 per lane.
template <int C, bool FINAL>
__global__ __launch_bounds__(256) void agg_kernel(
    const int* __restrict__ off, const int* __restrict__ ssrc,
    const float* __restrict__ als, const float* __restrict__ ald,
    const float* __restrict__ h, const float* __restrict__ bias,
    float* __restrict__ outp) {
    __shared__ int   sS[4][SEG_CAP];
    __shared__ float sW[4][SEG_CAP];
    const int wv = threadIdx.x >> 6;
    const int lane = threadIdx.x & 63;
    const int d = (blockIdx.x * blockDim.x + threadIdx.x) >> 6;
    if (d >= N_NODES) return;
    const int o0 = off[d];
    const int deg = off[d + 1] - o0;
    const float aldd = ald[d];

    // ---- phase A: stage s,e ; segment max ----
    float mloc = -1e30f;
    for (int t = lane; t < deg; t += 64) {
        int s = ssrc[o0 + t];
        float e = als[s] + aldd;
        e = e > 0.f ? e : NEG_SLOPE * e;
        if (t < SEG_CAP) { sS[wv][t] = s; sW[wv][t] = e; }
        mloc = fmaxf(mloc, e);
    }
#pragma unroll
    for (int o = 32; o; o >>= 1) mloc = fmaxf(mloc, __shfl_xor(mloc, o));

    // ---- phase B: w = exp(e-m), stage w ; segment sum ----
    float sloc = 0.f;
    for (int t = lane; t < deg; t += 64) {
        float e;
        if (t < SEG_CAP) e = sW[wv][t];
        else { float ee = als[ssrc[o0 + t]] + aldd; e = ee > 0.f ? ee : NEG_SLOPE * ee; }
        float w = __expf(e - mloc);
        if (t < SEG_CAP) sW[wv][t] = w;
        sloc += w;
    }
#pragma unroll
    for (int o = 32; o; o >>= 1) sloc += __shfl_xor(sloc, o);
    const float inv = 1.0f / (sloc + 1e-16f);

    // ---- phase C: half-wave per edge, float2 per lane, unroll x2 ----
    constexpr int CH2 = C / 2;
    const int half = lane >> 5;
    const int hl = lane & 31;
    float ax = 0.f, ay = 0.f;

    auto fetch_sw = [&](int t, int& s, float& w) {
        if (t < SEG_CAP) { s = sS[wv][t]; w = sW[wv][t]; }
        else {
            s = ssrc[o0 + t];
            float e = als[s] + aldd;
            e = e > 0.f ? e : NEG_SLOPE * e;
            w = __expf(e - mloc);
        }
    };

    int t = half;
    for (; t <= deg - 3; t += 4) {
        int s0, s1; float w0, w1;
        fetch_sw(t, s0, w0);
        fetch_sw(t + 2, s1, w1);
        if (hl < CH2) {
            const float2 h0 = *reinterpret_cast<const float2*>(h + (size_t)s0 * C + 2 * hl);
            const float2 h1 = *reinterpret_cast<const float2*>(h + (size_t)s1 * C + 2 * hl);
            ax += w0 * h0.x + w1 * h1.x;
            ay += w0 * h0.y + w1 * h1.y;
        }
    }
    if (t < deg) {
        int s0; float w0;
        fetch_sw(t, s0, w0);
        if (hl < CH2) {
            const float2 h0 = *reinterpret_cast<const float2*>(h + (size_t)s0 * C + 2 * hl);
            ax += w0 * h0.x;
            ay += w0 * h0.y;
        }
    }
    // combine the two half-wave partial sums
    ax += __shfl_xor(ax, 32);
    ay += __shfl_xor(ay, 32);

    const bool valid = (half == 0) && (hl < CH2);
    if (!FINAL) {
        if (valid) {
            const float2 bb = reinterpret_cast<const float2*>(bias)[hl];
            float2 v;
            v.x = ax * inv + bb.x;
            v.y = ay * inv + bb.y;
            v.x = v.x > 0.f ? v.x : 0.f;
            v.y = v.y > 0.f ? v.y : 0.f;
            *reinterpret_cast<float2*>(outp + (size_t)d * C + 2 * hl) = v;
        }
    } else {
        float vx = 0.f, vy = 0.f, mm = -1e30f;
        if (valid) {
            const float2 bb = reinterpret_cast<const float2*>(bias)[hl];
            vx = ax * inv + bb.x;
            vy = ay * inv + bb.y;
            mm = fmaxf(vx, vy);
        }
#pragma unroll
        for (int o = 32; o; o >>= 1) mm = fmaxf(mm, __shfl_xor(mm, o));
        float ex = valid ? (__expf(vx - mm) + __expf(vy - mm)) : 0.f;
#pragma unroll
        for (int o = 32; o; o >>= 1) ex += __shfl_xor(ex, o);
        if (valid) {
            const float lse = mm + logf(ex);
            float2 v; v.x = vx - lse; v.y = vy - lse;
            *reinterpret_cast<float2*>(outp + (size_t)d * C + 2 * hl) = v;
        }
    }
}

extern "C" void kernel_launch(void* const* d_in, const int* in_sizes, int n_in,
                              void* d_out, int out_size, void* d_ws, size_t ws_size,
                              hipStream_t stream) {
    const float* x   = (const float*)d_in[0];
    const int*   ei  = (const int*)d_in[1];
    const float* W1  = (const float*)d_in[2];
    const float* as1 = (const float*)d_in[3];
    const float* ad1 = (const float*)d_in[4];
    const float* b1  = (const float*)d_in[5];
    const float* W2  = (const float*)d_in[6];
    const float* as2 = (const float*)d_in[7];
    const float* ad2 = (const float*)d_in[8];
    const float* b2  = (const float*)d_in[9];
    float* out = (float*)d_out;

    float* A    = (float*)d_ws;                        // N*64 : h1, then h2 (N*40)
    float* B    = A + (size_t)N_NODES * 64;            // N*64 : layer-1 output / gemm2 input
    float* als  = B + (size_t)N_NODES * 64;            // N
    float* ald  = als + N_NODES;                       // N
    int* cnt    = (int*)(ald + N_NODES);               // N (reused as cursor)
    int* off    = cnt + N_NODES;                       // N+1
    int* blockSum = off + (N_NODES + 1);               // 256 pad
    int* ssrc   = blockSum + 256;                      // ETOT

    const int* srcA = ei;
    const int* dstA = ei + N_EDGESC;

    // ---- build dst-sorted edge structure (shared by both layers) ----
    hipMemsetAsync(cnt, 0, N_NODES * sizeof(int), stream);
    hist_kernel<<<(ETOT + 255) / 256, 256, 0, stream>>>(dstA, cnt);
    scanA_kernel<<<NSCAN_BLOCKS, 256, 0, stream>>>(cnt, off, blockSum);
    scanB_kernel<<<1, 128, 0, stream>>>(blockSum);
    scanC_kernel<<<(N_NODES + 255) / 256, 256, 0, stream>>>(off, blockSum, cnt);
    scatter_kernel<<<(ETOT + 255) / 256, 256, 0, stream>>>(srcA, dstA, cnt, ssrc);

    // ---- layer 1 ----
    gemm1_kernel<<<(N_NODES + 255) / 256, 256, 0, stream>>>(x, W1, as1, ad1, A, als, ald);
    agg_kernel<HID, false><<<(N_NODES * 64 + 255) / 256, 256, 0, stream>>>(off, ssrc, als, ald, A, b1, B);

    // ---- layer 2 ----
    gemm2_kernel<<<(N_NODES + 255) / 256, 256, 0, stream>>>(B, W2, as2, ad2, A, als, ald);
    agg_kernel<OUTC, true><<<(N_NODES * 64 + 255) / 256, 256, 0, stream>>>(off, ssrc, als, ald, A, b2, out);
}